// Round 12
// baseline (139.840 us; speedup 1.0000x reference)
//
#include <hip/hip_runtime.h>

// ---------------------------------------------------------------------------
// SGConv (K=2): out = A^2 (X W^T) + b,  A = D^{-1/2}(Adj_clamped + I)D^{-1/2}
// N=50000, E=800000, T=256, H=128. edge_index arrives as int32.
//
// r12 = r11 + two fixes:
//  (a) custom k_zero kernel replaces hipMemsetAsync(tails) (fillBufferAligned
//      measured 41us for 784B in r11 profile).
//  (b) transform: sched_barrier(0) fence after issuing ALL staging+W loads —
//      r11's compiler fused load/convert loops (VGPR 76 => 1 outstanding
//      load). Fence forces 40 loads in flight (VGPR ~200, fits 256,2).
// CSR build: two-pass bucket sort (r8). Hops: unroll-8 gather (r7).
// ---------------------------------------------------------------------------

typedef __attribute__((ext_vector_type(8))) short short8_t;   // 8 bf16
typedef __attribute__((ext_vector_type(4))) float f32x4_t;    // MFMA acc

constexpr int BK    = 256;   // nodes per bucket
constexpr int CAP   = 8192;  // records per bucket (mean 4096 + 64 sigma)
constexpr int CHUNK = 4096;  // edges per passA block

__device__ inline unsigned short f2bf(float f) {               // RNE f32->bf16
    unsigned int u = __float_as_uint(f);
    return (unsigned short)((u + 0x7fffu + ((u >> 16) & 1u)) >> 16);
}
__device__ inline float bf_lo(unsigned int u) { return __uint_as_float(u << 16); }
__device__ inline float bf_hi(unsigned int u) { return __uint_as_float(u & 0xffff0000u); }

// ---- zero the bucket tails (replaces 41us fillBufferAligned) ----
__global__ __launch_bounds__(256) void k_zero(int* __restrict__ p, int n)
{
    int i = blockIdx.x * 256 + threadIdx.x;
    if (i < n) p[i] = 0;
}

// ---- passA: bucket-bin edges; coalesced appends to bucket storage ----
__global__ __launch_bounds__(256) void k_passA(
    const int* __restrict__ rows, const int* __restrict__ cols,
    const float* __restrict__ ew, int E,
    unsigned int* __restrict__ bwr,   // [NB*CAP]  w<<16|row
    unsigned char* __restrict__ bcl,  // [NB*CAP]  col low byte
    int* __restrict__ tails,          // [NB]
    const float* __restrict__ W, unsigned short* __restrict__ Wbf, int WT)
{
    const int tid = threadIdx.x;
    const int gid = blockIdx.x * 256 + tid;
    if (gid < WT) Wbf[gid] = f2bf(W[gid]);       // fold W->bf16 conversion

    __shared__ unsigned short lcol[CHUNK], lrow[CHUNK], lw[CHUNK];
    __shared__ unsigned short sidx[CHUNK];
    __shared__ int hist[256], lofs[256], fill[256], gbase[256];

    const int e0  = blockIdx.x * CHUNK;
    const int cnt = min(CHUNK, E - e0);
    if (cnt <= 0) return;

    hist[tid] = 0; fill[tid] = 0;
    __syncthreads();

    for (int i = tid; i < cnt; i += 256) {
        const int c = cols[e0 + i];
        const int r = rows[e0 + i];
        float w = ew[e0 + i];
        w = (w > 0.0f) ? w : 1e-7f;              // elu(w)<=0 <=> w<=0
        lcol[i] = (unsigned short)c;
        lrow[i] = (unsigned short)r;
        lw[i]   = f2bf(w);
        atomicAdd(&hist[c >> 8], 1);
    }
    __syncthreads();

    // exclusive scan of hist -> lofs
    {
        const int v = hist[tid];
        lofs[tid] = v;
        __syncthreads();
        for (int off = 1; off < 256; off <<= 1) {
            int t = (tid >= off) ? lofs[tid - off] : 0;
            __syncthreads();
            lofs[tid] += t;
            __syncthreads();
        }
        const int excl = lofs[tid] - v;
        __syncthreads();
        lofs[tid] = excl;
        __syncthreads();
    }

    // rank within block -> sorted index
    for (int i = tid; i < cnt; i += 256) {
        const int b = lcol[i] >> 8;
        const int pos = lofs[b] + atomicAdd(&fill[b], 1);
        sidx[pos] = (unsigned short)i;
    }
    __syncthreads();

    // reserve global space: one atomic per non-empty bucket
    {
        const int h = hist[tid];
        gbase[tid] = (h > 0) ? atomicAdd(&tails[tid], h) : 0;
    }
    __syncthreads();

    // write out in bucket-sorted order (runs of consecutive addresses)
    for (int i = tid; i < cnt; i += 256) {
        const int e = sidx[i];
        const int b = lcol[e] >> 8;
        const int slot = gbase[b] + (i - lofs[b]);
        if (slot < CAP) {                         // overflow guard
            const int addr = b * CAP + slot;
            bwr[addr] = ((unsigned int)lw[e] << 16) | lrow[e];
            bcl[addr] = (unsigned char)(lcol[e] & 255);
        }
    }
}

// ---- passB: per-bucket LDS sort + dis/starts/ends; coalesced meta write ----
__global__ __launch_bounds__(256) void k_passB(
    const unsigned int* __restrict__ bwr, const unsigned char* __restrict__ bcl,
    const int* __restrict__ tails,
    unsigned int* __restrict__ meta, int* __restrict__ starts,
    int* __restrict__ ends, float* __restrict__ dis, int N)
{
    const int tid  = threadIdx.x;
    const int b    = blockIdx.x;
    const int base = b * CAP;
    const int cnt  = min(tails[b], CAP);

    __shared__ unsigned int  lwr[CAP];      // 32 KB
    __shared__ unsigned char lcl[CAP];      // 8 KB
    __shared__ unsigned int  srt[CAP];      // 32 KB
    __shared__ int hist[256], offs[256], fill[256];

    hist[tid] = 0; fill[tid] = 0;
    __syncthreads();

    for (int i = tid; i < cnt; i += 256) {
        lwr[i] = bwr[base + i];
        unsigned char c = bcl[base + i];
        lcl[i] = c;
        atomicAdd(&hist[c], 1);
    }
    __syncthreads();

    // exclusive scan of hist -> offs
    {
        const int v = hist[tid];
        offs[tid] = v;
        __syncthreads();
        for (int off = 1; off < 256; off <<= 1) {
            int t = (tid >= off) ? offs[tid - off] : 0;
            __syncthreads();
            offs[tid] += t;
            __syncthreads();
        }
        const int excl = offs[tid] - v;
        __syncthreads();
        offs[tid] = excl;
        __syncthreads();
    }

    // scatter to sorted order (LDS -> LDS)
    for (int i = tid; i < cnt; i += 256) {
        const int c = lcl[i];
        const int pos = offs[c] + atomicAdd(&fill[c], 1);
        srt[pos] = lwr[i];
    }
    __syncthreads();

    // coalesced meta write
    for (int i = tid; i < cnt; i += 256) meta[base + i] = srt[i];

    // per-node: dis = rsqrt(1 + sum w), starts/ends
    const int node = b * BK + tid;
    if (node < N) {
        const int s = offs[tid];
        const int t = s + hist[tid];
        float sum = 1.0f;                         // self-loop
        for (int j = s; j < t; ++j) sum += bf_hi(srt[j]);
        dis[node]    = rsqrtf(sum);
        starts[node] = base + s;
        ends[node]   = base + t;
    }
}

// ---- z[r][h] = bf16( dis[r] * dot(x[r], W[h]) ) via MFMA bf16 ----
// r12: all 40 loads issued, sched_barrier(0) fence, then convert/consume.
__global__ __launch_bounds__(256, 2) void k_transform_mfma(
    const float* __restrict__ x, const unsigned short* __restrict__ Wbf,
    const float* __restrict__ dis, unsigned short* __restrict__ z, int N)
{
    constexpr int RB  = 32;
    constexpr int LDK = 264;   // 256 + 8 pad shorts; row stride 528 B
    __shared__ unsigned short xs[RB][LDK];

    const int tid  = threadIdx.x;
    const int r0   = blockIdx.x * RB;
    const int wave = tid >> 6;
    const int lane = tid & 63;
    const int lr   = lane & 15;     // A-row / D-col within tile
    const int kg   = lane >> 4;     // k-group (8 consecutive k each)
    const int nb   = (wave & 1) * 4;    // n-tile base: cols nb*16 .. nb*16+63
    const int wr0  = (wave >> 1) * 16;  // row offset within block (0 or 16)

    // ---- issue ALL loads first: 8 x-staging float4 + 32 W fragments ----
    const float4* x4 = reinterpret_cast<const float4*>(x);
    float4 v[8];
#pragma unroll
    for (int it = 0; it < 8; ++it) {
        const int i   = it * 256 + tid;          // RB*64 = 2048 = 8*256
        const int row = r0 + (i >> 6);
        v[it] = (row < N) ? x4[(size_t)row * 64 + (i & 63)]
                          : make_float4(0.f, 0.f, 0.f, 0.f);
    }
    short8_t wf[4][8];
#pragma unroll
    for (int n = 0; n < 4; ++n)
#pragma unroll
        for (int k = 0; k < 8; ++k)
            wf[n][k] = *reinterpret_cast<const short8_t*>(
                Wbf + (size_t)((nb + n) * 16 + lr) * 256 + k * 32 + kg * 8);

    // fence: nothing crosses — loads stay clustered above (40 in flight)
    __builtin_amdgcn_sched_barrier(0);

    // convert + LDS write (waitcnt drains oldest-first as we consume v[])
#pragma unroll
    for (int it = 0; it < 8; ++it) {
        const int i = it * 256 + tid;
        unsigned short* p = &xs[i >> 6][(i & 63) * 4];
        p[0] = f2bf(v[it].x); p[1] = f2bf(v[it].y);
        p[2] = f2bf(v[it].z); p[3] = f2bf(v[it].w);
    }
    __syncthreads();

    f32x4_t acc[4];
#pragma unroll
    for (int n = 0; n < 4; ++n) acc[n] = (f32x4_t){0.f, 0.f, 0.f, 0.f};

#pragma unroll
    for (int k = 0; k < 8; ++k) {
        const short8_t af =
            *reinterpret_cast<const short8_t*>(&xs[wr0 + lr][k * 32 + kg * 8]);
#pragma unroll
        for (int n = 0; n < 4; ++n)
            acc[n] = __builtin_amdgcn_mfma_f32_16x16x32_bf16(af, wf[n][k],
                                                             acc[n], 0, 0, 0);
    }

    // D layout: col = lane&15, row = (lane>>4)*4 + reg   [m89/m91]
    float dsc[4];
#pragma unroll
    for (int r = 0; r < 4; ++r) {
        const int orow = r0 + wr0 + kg * 4 + r;
        dsc[r] = (orow < N) ? dis[orow] : 0.f;
    }
#pragma unroll
    for (int n = 0; n < 4; ++n) {
#pragma unroll
        for (int r = 0; r < 4; ++r) {
            const int orow = r0 + wr0 + kg * 4 + r;
            if (orow < N)
                z[(size_t)orow * 128 + (nb + n) * 16 + lr] =
                    f2bf(dsc[r] * acc[n][r]);
        }
    }
}

// ---- hop: one wave per dst node, unroll-8 independent gathers ----
// acc = z[c] + sum w*z[r];  FINAL: out=dis*acc+bias (f32); else bf16(dis^2*acc)
template <bool FINAL>
__global__ __launch_bounds__(256) void k_hop(
    const int* __restrict__ starts, const int* __restrict__ ends,
    const unsigned int* __restrict__ meta,
    const float* __restrict__ dis, const unsigned int* __restrict__ hin,
    const float* __restrict__ bias, void* __restrict__ hout, int N)
{
    const int wave = threadIdx.x >> 6;
    const int lane = threadIdx.x & 63;
    const int node = blockIdx.x * 4 + wave;
    if (node >= N) return;

    const int s = __builtin_amdgcn_readfirstlane(starts[node]);
    const int t = __builtin_amdgcn_readfirstlane(ends[node]);
    const float d = dis[node];

    unsigned int v = hin[(size_t)node * 64 + lane];
    float ax = bf_lo(v), ay = bf_hi(v);            // self term z[c]

    int j = s;
    for (; j + 8 <= t; j += 8) {
        unsigned int m0 = meta[j],     m1 = meta[j + 1];
        unsigned int m2 = meta[j + 2], m3 = meta[j + 3];
        unsigned int m4 = meta[j + 4], m5 = meta[j + 5];
        unsigned int m6 = meta[j + 6], m7 = meta[j + 7];
        unsigned int u0 = hin[(size_t)(m0 & 0xffffu) * 64 + lane];
        unsigned int u1 = hin[(size_t)(m1 & 0xffffu) * 64 + lane];
        unsigned int u2 = hin[(size_t)(m2 & 0xffffu) * 64 + lane];
        unsigned int u3 = hin[(size_t)(m3 & 0xffffu) * 64 + lane];
        unsigned int u4 = hin[(size_t)(m4 & 0xffffu) * 64 + lane];
        unsigned int u5 = hin[(size_t)(m5 & 0xffffu) * 64 + lane];
        unsigned int u6 = hin[(size_t)(m6 & 0xffffu) * 64 + lane];
        unsigned int u7 = hin[(size_t)(m7 & 0xffffu) * 64 + lane];
        ax += bf_hi(m0) * bf_lo(u0); ay += bf_hi(m0) * bf_hi(u0);
        ax += bf_hi(m1) * bf_lo(u1); ay += bf_hi(m1) * bf_hi(u1);
        ax += bf_hi(m2) * bf_lo(u2); ay += bf_hi(m2) * bf_hi(u2);
        ax += bf_hi(m3) * bf_lo(u3); ay += bf_hi(m3) * bf_hi(u3);
        ax += bf_hi(m4) * bf_lo(u4); ay += bf_hi(m4) * bf_hi(u4);
        ax += bf_hi(m5) * bf_lo(u5); ay += bf_hi(m5) * bf_hi(u5);
        ax += bf_hi(m6) * bf_lo(u6); ay += bf_hi(m6) * bf_hi(u6);
        ax += bf_hi(m7) * bf_lo(u7); ay += bf_hi(m7) * bf_hi(u7);
    }
    for (; j < t; ++j) {
        unsigned int m = meta[j];
        const float w = bf_hi(m);
        unsigned int u = hin[(size_t)(m & 0xffffu) * 64 + lane];
        ax += w * bf_lo(u); ay += w * bf_hi(u);
    }

    if (FINAL) {
        float2 bv = reinterpret_cast<const float2*>(bias)[lane];
        float2 o; o.x = d * ax + bv.x; o.y = d * ay + bv.y;
        reinterpret_cast<float2*>(hout)[(size_t)node * 64 + lane] = o;
    } else {
        const float d2 = d * d;
        unsigned int p = (unsigned int)f2bf(d2 * ax) |
                         ((unsigned int)f2bf(d2 * ay) << 16);
        reinterpret_cast<unsigned int*>(hout)[(size_t)node * 64 + lane] = p;
    }
}

extern "C" void kernel_launch(void* const* d_in, const int* in_sizes, int n_in,
                              void* d_out, int out_size, void* d_ws, size_t ws_size,
                              hipStream_t stream)
{
    const float* x  = (const float*)d_in[0];
    const int*   ei = (const int*)d_in[1];     // int32 (harness converts)
    const float* ew = (const float*)d_in[2];
    const float* W  = (const float*)d_in[3];
    const float* b  = (const float*)d_in[4];

    const int E  = in_sizes[2];
    const int H  = in_sizes[4];        // 128
    const int T  = in_sizes[3] / H;    // 256
    const int N  = in_sizes[0] / T;    // 50000  (< 65536: 16-bit ids valid)
    const int WT = in_sizes[3];        // 32768
    const int NB = (N + BK - 1) / BK;  // 196 buckets

    const int* rows = ei;              // sources
    const int* cols = ei + E;          // targets (aggregation index)

    // ---- workspace ----
    char* wsb = (char*)d_ws;
    unsigned int*   z    = (unsigned int*)wsb;   wsb += (size_t)N * (H / 2) * 4;  // 12.8 MB
    unsigned int*   z1   = (unsigned int*)wsb;   wsb += (size_t)N * (H / 2) * 4;  // 12.8 MB
    unsigned int*   meta = (unsigned int*)wsb;   wsb += (size_t)NB * CAP * 4;     // 6.4 MB
    unsigned short* Wbf  = (unsigned short*)wsb; wsb += (size_t)WT * 2;           // 64 KB
    float*          dis  = (float*)wsb;          wsb += (size_t)N * 4;
    int*            sta  = (int*)wsb;            wsb += (size_t)N * 4;
    int*            end_ = (int*)wsb;            wsb += (size_t)N * 4;
    int*            tails= (int*)wsb;            wsb += (size_t)NB * 4;
    // bucket staging aliases z1 (dead until hop1 output): bwr 6.4MB + bcl 1.6MB
    unsigned int*   bwr  = z1;                                  // NB*CAP*4
    unsigned char*  bcl  = (unsigned char*)(z1 + (size_t)NB * CAP);

    float* out = (float*)d_out;

    // CSR build: bucket two-pass
    k_zero<<<(NB + 255) / 256, 256, 0, stream>>>(tails, NB);
    {
        const int nblkA = (E + CHUNK - 1) / CHUNK;   // 196 (covers WT too)
        k_passA<<<nblkA, 256, 0, stream>>>(rows, cols, ew, E,
                                           bwr, bcl, tails, W, Wbf, WT);
        k_passB<<<NB, 256, 0, stream>>>(bwr, bcl, tails,
                                        meta, sta, end_, dis, N);
    }

    // transform: z = bf16(dis * (X W^T))
    {
        const int RB = 32;
        k_transform_mfma<<<(N + RB - 1) / RB, 256, 0, stream>>>(
            x, Wbf, dis, (unsigned short*)z, N);
    }

    // hops (hop1 overwrites z1 -> bucket staging dead by then)
    const int gH = (N + 3) / 4;
    k_hop<false><<<gH, 256, 0, stream>>>(sta, end_, meta, dis, z, nullptr, z1, N);
    k_hop<true ><<<gH, 256, 0, stream>>>(sta, end_, meta, dis, z1, b, out, N);
}

// Round 13
// 139.368 us; speedup vs baseline: 1.0034x; 1.0034x over previous
//
#include <hip/hip_runtime.h>

// ---------------------------------------------------------------------------
// SGConv (K=2): out = A^2 (X W^T) + b,  A = D^{-1/2}(Adj_clamped + I)D^{-1/2}
// N=50000, E=800000, T=256, H=128. edge_index arrives as int32.
//
// r13: transform staging via __builtin_amdgcn_global_load_lds (async, no
// VGPR round-trip — r10/r11/r12 all failed to keep >1 load in flight at
// source level; VGPR count proved the compiler serialized them).
// x staged as raw f32, bank-swizzled via pre-swizzled GLOBAL source addr
// (LDS dest linear as required) + same XOR on ds_read. f32->bf16 at read.
// CSR build: two-pass bucket sort (r8). Hops: unroll-8 gather (r7).
// ---------------------------------------------------------------------------

typedef __attribute__((ext_vector_type(8))) short short8_t;   // 8 bf16
typedef __attribute__((ext_vector_type(4))) float f32x4_t;    // MFMA acc

constexpr int BK    = 256;   // nodes per bucket
constexpr int CAP   = 8192;  // records per bucket (mean 4096 + 64 sigma)
constexpr int CHUNK = 4096;  // edges per passA block

__device__ inline unsigned short f2bf(float f) {               // RNE f32->bf16
    unsigned int u = __float_as_uint(f);
    return (unsigned short)((u + 0x7fffu + ((u >> 16) & 1u)) >> 16);
}
__device__ inline float bf_lo(unsigned int u) { return __uint_as_float(u << 16); }
__device__ inline float bf_hi(unsigned int u) { return __uint_as_float(u & 0xffff0000u); }

// async 16B/lane global->LDS (wave-uniform LDS base + lane*16)
__device__ inline void async_load16(const void* g, void* l) {
    __builtin_amdgcn_global_load_lds(
        (const __attribute__((address_space(1))) unsigned int*)g,
        (__attribute__((address_space(3))) unsigned int*)l, 16, 0, 0);
}

// ---- zero the bucket tails ----
__global__ __launch_bounds__(256) void k_zero(int* __restrict__ p, int n)
{
    int i = blockIdx.x * 256 + threadIdx.x;
    if (i < n) p[i] = 0;
}

// ---- passA: bucket-bin edges; coalesced appends to bucket storage ----
__global__ __launch_bounds__(256) void k_passA(
    const int* __restrict__ rows, const int* __restrict__ cols,
    const float* __restrict__ ew, int E,
    unsigned int* __restrict__ bwr,   // [NB*CAP]  w<<16|row
    unsigned char* __restrict__ bcl,  // [NB*CAP]  col low byte
    int* __restrict__ tails,          // [NB]
    const float* __restrict__ W, unsigned short* __restrict__ Wbf, int WT)
{
    const int tid = threadIdx.x;
    const int gid = blockIdx.x * 256 + tid;
    if (gid < WT) Wbf[gid] = f2bf(W[gid]);       // fold W->bf16 conversion

    __shared__ unsigned short lcol[CHUNK], lrow[CHUNK], lw[CHUNK];
    __shared__ unsigned short sidx[CHUNK];
    __shared__ int hist[256], lofs[256], fill[256], gbase[256];

    const int e0  = blockIdx.x * CHUNK;
    const int cnt = min(CHUNK, E - e0);
    if (cnt <= 0) return;

    hist[tid] = 0; fill[tid] = 0;
    __syncthreads();

    for (int i = tid; i < cnt; i += 256) {
        const int c = cols[e0 + i];
        const int r = rows[e0 + i];
        float w = ew[e0 + i];
        w = (w > 0.0f) ? w : 1e-7f;              // elu(w)<=0 <=> w<=0
        lcol[i] = (unsigned short)c;
        lrow[i] = (unsigned short)r;
        lw[i]   = f2bf(w);
        atomicAdd(&hist[c >> 8], 1);
    }
    __syncthreads();

    // exclusive scan of hist -> lofs
    {
        const int v = hist[tid];
        lofs[tid] = v;
        __syncthreads();
        for (int off = 1; off < 256; off <<= 1) {
            int t = (tid >= off) ? lofs[tid - off] : 0;
            __syncthreads();
            lofs[tid] += t;
            __syncthreads();
        }
        const int excl = lofs[tid] - v;
        __syncthreads();
        lofs[tid] = excl;
        __syncthreads();
    }

    // rank within block -> sorted index
    for (int i = tid; i < cnt; i += 256) {
        const int b = lcol[i] >> 8;
        const int pos = lofs[b] + atomicAdd(&fill[b], 1);
        sidx[pos] = (unsigned short)i;
    }
    __syncthreads();

    // reserve global space: one atomic per non-empty bucket
    {
        const int h = hist[tid];
        gbase[tid] = (h > 0) ? atomicAdd(&tails[tid], h) : 0;
    }
    __syncthreads();

    // write out in bucket-sorted order (runs of consecutive addresses)
    for (int i = tid; i < cnt; i += 256) {
        const int e = sidx[i];
        const int b = lcol[e] >> 8;
        const int slot = gbase[b] + (i - lofs[b]);
        if (slot < CAP) {                         // overflow guard
            const int addr = b * CAP + slot;
            bwr[addr] = ((unsigned int)lw[e] << 16) | lrow[e];
            bcl[addr] = (unsigned char)(lcol[e] & 255);
        }
    }
}

// ---- passB: per-bucket LDS sort + dis/starts/ends; coalesced meta write ----
__global__ __launch_bounds__(256) void k_passB(
    const unsigned int* __restrict__ bwr, const unsigned char* __restrict__ bcl,
    const int* __restrict__ tails,
    unsigned int* __restrict__ meta, int* __restrict__ starts,
    int* __restrict__ ends, float* __restrict__ dis, int N)
{
    const int tid  = threadIdx.x;
    const int b    = blockIdx.x;
    const int base = b * CAP;
    const int cnt  = min(tails[b], CAP);

    __shared__ unsigned int  lwr[CAP];      // 32 KB
    __shared__ unsigned char lcl[CAP];      // 8 KB
    __shared__ unsigned int  srt[CAP];      // 32 KB
    __shared__ int hist[256], offs[256], fill[256];

    hist[tid] = 0; fill[tid] = 0;
    __syncthreads();

    for (int i = tid; i < cnt; i += 256) {
        lwr[i] = bwr[base + i];
        unsigned char c = bcl[base + i];
        lcl[i] = c;
        atomicAdd(&hist[c], 1);
    }
    __syncthreads();

    // exclusive scan of hist -> offs
    {
        const int v = hist[tid];
        offs[tid] = v;
        __syncthreads();
        for (int off = 1; off < 256; off <<= 1) {
            int t = (tid >= off) ? offs[tid - off] : 0;
            __syncthreads();
            offs[tid] += t;
            __syncthreads();
        }
        const int excl = offs[tid] - v;
        __syncthreads();
        offs[tid] = excl;
        __syncthreads();
    }

    // scatter to sorted order (LDS -> LDS)
    for (int i = tid; i < cnt; i += 256) {
        const int c = lcl[i];
        const int pos = offs[c] + atomicAdd(&fill[c], 1);
        srt[pos] = lwr[i];
    }
    __syncthreads();

    // coalesced meta write
    for (int i = tid; i < cnt; i += 256) meta[base + i] = srt[i];

    // per-node: dis = rsqrt(1 + sum w), starts/ends
    const int node = b * BK + tid;
    if (node < N) {
        const int s = offs[tid];
        const int t = s + hist[tid];
        float sum = 1.0f;                         // self-loop
        for (int j = s; j < t; ++j) sum += bf_hi(srt[j]);
        dis[node]    = rsqrtf(sum);
        starts[node] = base + s;
        ends[node]   = base + t;
    }
}

// ---- z[r][h] = bf16( dis[r] * dot(x[r], W[h]) ) via MFMA bf16 ----
// r13: async global_load_lds staging (f32, swizzled source), W in VGPRs.
__global__ __launch_bounds__(256, 2) void k_transform_mfma(
    const float* __restrict__ x, const unsigned short* __restrict__ Wbf,
    const float* __restrict__ dis, unsigned short* __restrict__ z, int N)
{
    constexpr int RB = 32;
    __shared__ float xs[RB][256];       // 32 KB, LINEAR (global_load_lds dest)

    const int tid  = threadIdx.x;
    const int r0   = blockIdx.x * RB;
    const int wave = tid >> 6;
    const int lane = tid & 63;
    const int lr   = lane & 15;     // A-row / D-col within tile
    const int kg   = lane >> 4;     // k-group (8 consecutive k each)
    const int nb   = (wave & 1) * 4;    // n-tile base: cols nb*16 .. nb*16+63
    const int wr0  = (wave >> 1) * 16;  // row offset within block (0 or 16)

    // ---- async stage: wave w stages rows 8w..8w+7, 1 KB per instruction.
    // Global source pre-swizzled (lane*16 ^ (row&7)<<4); LDS stays linear.
#pragma unroll
    for (int r = 0; r < 8; ++r) {
        const int row  = wave * 8 + r;
        const int grow = r0 + row;
        if (grow < N) {
            const char* src = (const char*)(x + (size_t)grow * 256)
                              + ((lane * 16) ^ ((row & 7) << 4));
            async_load16(src, &xs[row][0]);
        } else {
            *(float4*)((char*)&xs[row][0] + lane * 16) =
                make_float4(0.f, 0.f, 0.f, 0.f);
        }
    }

    // W preload: 32 independent 16B loads (L2-broadcast), overlaps staging
    short8_t wf[4][8];
#pragma unroll
    for (int n = 0; n < 4; ++n)
#pragma unroll
        for (int k = 0; k < 8; ++k)
            wf[n][k] = *reinterpret_cast<const short8_t*>(
                Wbf + (size_t)((nb + n) * 16 + lr) * 256 + k * 32 + kg * 8);

    __syncthreads();   // compiler inserts s_waitcnt vmcnt(0) before barrier

    f32x4_t acc[4];
#pragma unroll
    for (int n = 0; n < 4; ++n) acc[n] = (f32x4_t){0.f, 0.f, 0.f, 0.f};

    const char* xb = (const char*)&xs[0][0];
    const int   row = wr0 + lr;
    const int   sw  = (row & 7) << 4;

#pragma unroll
    for (int k = 0; k < 8; ++k) {
        // want global bytes [g, g+32) of this row; LDS[p] = global[p^sw]
        const int g  = k * 128 + kg * 32;
        const int a0 = row * 1024 + (g ^ sw);
        const int a1 = row * 1024 + ((g + 16) ^ sw);
        float4 f0 = *(const float4*)(xb + a0);
        float4 f1 = *(const float4*)(xb + a1);
        short8_t af;
        af[0] = (short)f2bf(f0.x); af[1] = (short)f2bf(f0.y);
        af[2] = (short)f2bf(f0.z); af[3] = (short)f2bf(f0.w);
        af[4] = (short)f2bf(f1.x); af[5] = (short)f2bf(f1.y);
        af[6] = (short)f2bf(f1.z); af[7] = (short)f2bf(f1.w);
#pragma unroll
        for (int n = 0; n < 4; ++n)
            acc[n] = __builtin_amdgcn_mfma_f32_16x16x32_bf16(af, wf[n][k],
                                                             acc[n], 0, 0, 0);
    }

    // D layout: col = lane&15, row = (lane>>4)*4 + reg   [m89/m91]
    float dsc[4];
#pragma unroll
    for (int r = 0; r < 4; ++r) {
        const int orow = r0 + wr0 + kg * 4 + r;
        dsc[r] = (orow < N) ? dis[orow] : 0.f;
    }
#pragma unroll
    for (int n = 0; n < 4; ++n) {
#pragma unroll
        for (int r = 0; r < 4; ++r) {
            const int orow = r0 + wr0 + kg * 4 + r;
            if (orow < N)
                z[(size_t)orow * 128 + (nb + n) * 16 + lr] =
                    f2bf(dsc[r] * acc[n][r]);
        }
    }
}

// ---- hop: one wave per dst node, unroll-8 independent gathers ----
// acc = z[c] + sum w*z[r];  FINAL: out=dis*acc+bias (f32); else bf16(dis^2*acc)
template <bool FINAL>
__global__ __launch_bounds__(256) void k_hop(
    const int* __restrict__ starts, const int* __restrict__ ends,
    const unsigned int* __restrict__ meta,
    const float* __restrict__ dis, const unsigned int* __restrict__ hin,
    const float* __restrict__ bias, void* __restrict__ hout, int N)
{
    const int wave = threadIdx.x >> 6;
    const int lane = threadIdx.x & 63;
    const int node = blockIdx.x * 4 + wave;
    if (node >= N) return;

    const int s = __builtin_amdgcn_readfirstlane(starts[node]);
    const int t = __builtin_amdgcn_readfirstlane(ends[node]);
    const float d = dis[node];

    unsigned int v = hin[(size_t)node * 64 + lane];
    float ax = bf_lo(v), ay = bf_hi(v);            // self term z[c]

    int j = s;
    for (; j + 8 <= t; j += 8) {
        unsigned int m0 = meta[j],     m1 = meta[j + 1];
        unsigned int m2 = meta[j + 2], m3 = meta[j + 3];
        unsigned int m4 = meta[j + 4], m5 = meta[j + 5];
        unsigned int m6 = meta[j + 6], m7 = meta[j + 7];
        unsigned int u0 = hin[(size_t)(m0 & 0xffffu) * 64 + lane];
        unsigned int u1 = hin[(size_t)(m1 & 0xffffu) * 64 + lane];
        unsigned int u2 = hin[(size_t)(m2 & 0xffffu) * 64 + lane];
        unsigned int u3 = hin[(size_t)(m3 & 0xffffu) * 64 + lane];
        unsigned int u4 = hin[(size_t)(m4 & 0xffffu) * 64 + lane];
        unsigned int u5 = hin[(size_t)(m5 & 0xffffu) * 64 + lane];
        unsigned int u6 = hin[(size_t)(m6 & 0xffffu) * 64 + lane];
        unsigned int u7 = hin[(size_t)(m7 & 0xffffu) * 64 + lane];
        ax += bf_hi(m0) * bf_lo(u0); ay += bf_hi(m0) * bf_hi(u0);
        ax += bf_hi(m1) * bf_lo(u1); ay += bf_hi(m1) * bf_hi(u1);
        ax += bf_hi(m2) * bf_lo(u2); ay += bf_hi(m2) * bf_hi(u2);
        ax += bf_hi(m3) * bf_lo(u3); ay += bf_hi(m3) * bf_hi(u3);
        ax += bf_hi(m4) * bf_lo(u4); ay += bf_hi(m4) * bf_hi(u4);
        ax += bf_hi(m5) * bf_lo(u5); ay += bf_hi(m5) * bf_hi(u5);
        ax += bf_hi(m6) * bf_lo(u6); ay += bf_hi(m6) * bf_hi(u6);
        ax += bf_hi(m7) * bf_lo(u7); ay += bf_hi(m7) * bf_hi(u7);
    }
    for (; j < t; ++j) {
        unsigned int m = meta[j];
        const float w = bf_hi(m);
        unsigned int u = hin[(size_t)(m & 0xffffu) * 64 + lane];
        ax += w * bf_lo(u); ay += w * bf_hi(u);
    }

    if (FINAL) {
        float2 bv = reinterpret_cast<const float2*>(bias)[lane];
        float2 o; o.x = d * ax + bv.x; o.y = d * ay + bv.y;
        reinterpret_cast<float2*>(hout)[(size_t)node * 64 + lane] = o;
    } else {
        const float d2 = d * d;
        unsigned int p = (unsigned int)f2bf(d2 * ax) |
                         ((unsigned int)f2bf(d2 * ay) << 16);
        reinterpret_cast<unsigned int*>(hout)[(size_t)node * 64 + lane] = p;
    }
}

extern "C" void kernel_launch(void* const* d_in, const int* in_sizes, int n_in,
                              void* d_out, int out_size, void* d_ws, size_t ws_size,
                              hipStream_t stream)
{
    const float* x  = (const float*)d_in[0];
    const int*   ei = (const int*)d_in[1];     // int32 (harness converts)
    const float* ew = (const float*)d_in[2];
    const float* W  = (const float*)d_in[3];
    const float* b  = (const float*)d_in[4];

    const int E  = in_sizes[2];
    const int H  = in_sizes[4];        // 128
    const int T  = in_sizes[3] / H;    // 256
    const int N  = in_sizes[0] / T;    // 50000  (< 65536: 16-bit ids valid)
    const int WT = in_sizes[3];        // 32768
    const int NB = (N + BK - 1) / BK;  // 196 buckets

    const int* rows = ei;              // sources
    const int* cols = ei + E;          // targets (aggregation index)

    // ---- workspace ----
    char* wsb = (char*)d_ws;
    unsigned int*   z    = (unsigned int*)wsb;   wsb += (size_t)N * (H / 2) * 4;  // 12.8 MB
    unsigned int*   z1   = (unsigned int*)wsb;   wsb += (size_t)N * (H / 2) * 4;  // 12.8 MB
    unsigned int*   meta = (unsigned int*)wsb;   wsb += (size_t)NB * CAP * 4;     // 6.4 MB
    unsigned short* Wbf  = (unsigned short*)wsb; wsb += (size_t)WT * 2;           // 64 KB
    float*          dis  = (float*)wsb;          wsb += (size_t)N * 4;
    int*            sta  = (int*)wsb;            wsb += (size_t)N * 4;
    int*            end_ = (int*)wsb;            wsb += (size_t)N * 4;
    int*            tails= (int*)wsb;            wsb += (size_t)NB * 4;
    // bucket staging aliases z1 (dead until hop1 output): bwr 6.4MB + bcl 1.6MB
    unsigned int*   bwr  = z1;                                  // NB*CAP*4
    unsigned char*  bcl  = (unsigned char*)(z1 + (size_t)NB * CAP);

    float* out = (float*)d_out;

    // CSR build: bucket two-pass
    k_zero<<<(NB + 255) / 256, 256, 0, stream>>>(tails, NB);
    {
        const int nblkA = (E + CHUNK - 1) / CHUNK;   // 196 (covers WT too)
        k_passA<<<nblkA, 256, 0, stream>>>(rows, cols, ew, E,
                                           bwr, bcl, tails, W, Wbf, WT);
        k_passB<<<NB, 256, 0, stream>>>(bwr, bcl, tails,
                                        meta, sta, end_, dis, N);
    }

    // transform: z = bf16(dis * (X W^T))
    {
        const int RB = 32;
        k_transform_mfma<<<(N + RB - 1) / RB, 256, 0, stream>>>(
            x, Wbf, dis, (unsigned short*)z, N);
    }

    // hops (hop1 overwrites z1 -> bucket staging dead by then)
    const int gH = (N + 3) / 4;
    k_hop<false><<<gH, 256, 0, stream>>>(sta, end_, meta, dis, z, nullptr, z1, N);
    k_hop<true ><<<gH, 256, 0, stream>>>(sta, end_, meta, dis, z1, b, out, N);
}

// Round 14
// 135.304 us; speedup vs baseline: 1.0335x; 1.0300x over previous
//
#include <hip/hip_runtime.h>

// ---------------------------------------------------------------------------
// SGConv (K=2): out = A^2 (X W^T) + b,  A = D^{-1/2}(Adj_clamped + I)D^{-1/2}
// N=50000, E=800000, T=256, H=128. edge_index arrives as int32.
//
// r14: transform de-throttled:
//  (a) __launch_bounds__(256) only — r10-r13 had (256,2) which per guide
//      means "2 waves/EU" => 8 waves/CU cap => measured 23% occupancy.
//      TLP, not ILP, is the fix for this latency-bound kernel.
//  (b) W read in-loop from L2 (preload never stayed in VGPRs anyway).
//  (c) z stored in MFMA-fragment-permuted layout: thread stores 4x8B uint2
//      (was 16x2B scattered). Permutation is elementwise-transparent to
//      hop1; hop2 (FINAL) unwinds it analytically for bias/out.
//      col(p) for short-index p in a 128-col row: h=p>=64; p'=p-64h;
//      col = 64h + (p'&3)*16 + (p'>>2).
// CSR build: two-pass bucket sort (r8). Hops: unroll-8 gather (r7).
// ---------------------------------------------------------------------------

typedef __attribute__((ext_vector_type(8))) short short8_t;   // 8 bf16
typedef __attribute__((ext_vector_type(4))) float f32x4_t;    // MFMA acc

constexpr int BK    = 256;   // nodes per bucket
constexpr int CAP   = 8192;  // records per bucket (mean 4096 + 64 sigma)
constexpr int CHUNK = 4096;  // edges per passA block

__device__ inline unsigned short f2bf(float f) {               // RNE f32->bf16
    unsigned int u = __float_as_uint(f);
    return (unsigned short)((u + 0x7fffu + ((u >> 16) & 1u)) >> 16);
}
__device__ inline float bf_lo(unsigned int u) { return __uint_as_float(u << 16); }
__device__ inline float bf_hi(unsigned int u) { return __uint_as_float(u & 0xffff0000u); }

// async 16B/lane global->LDS (wave-uniform LDS base + lane*16)
__device__ inline void async_load16(const void* g, void* l) {
    __builtin_amdgcn_global_load_lds(
        (const __attribute__((address_space(1))) unsigned int*)g,
        (__attribute__((address_space(3))) unsigned int*)l, 16, 0, 0);
}

// ---- zero the bucket tails ----
__global__ __launch_bounds__(256) void k_zero(int* __restrict__ p, int n)
{
    int i = blockIdx.x * 256 + threadIdx.x;
    if (i < n) p[i] = 0;
}

// ---- passA: bucket-bin edges; coalesced appends to bucket storage ----
__global__ __launch_bounds__(256) void k_passA(
    const int* __restrict__ rows, const int* __restrict__ cols,
    const float* __restrict__ ew, int E,
    unsigned int* __restrict__ bwr,   // [NB*CAP]  w<<16|row
    unsigned char* __restrict__ bcl,  // [NB*CAP]  col low byte
    int* __restrict__ tails,          // [NB]
    const float* __restrict__ W, unsigned short* __restrict__ Wbf, int WT)
{
    const int tid = threadIdx.x;
    const int gid = blockIdx.x * 256 + tid;
    if (gid < WT) Wbf[gid] = f2bf(W[gid]);       // fold W->bf16 conversion

    __shared__ unsigned short lcol[CHUNK], lrow[CHUNK], lw[CHUNK];
    __shared__ unsigned short sidx[CHUNK];
    __shared__ int hist[256], lofs[256], fill[256], gbase[256];

    const int e0  = blockIdx.x * CHUNK;
    const int cnt = min(CHUNK, E - e0);
    if (cnt <= 0) return;

    hist[tid] = 0; fill[tid] = 0;
    __syncthreads();

    for (int i = tid; i < cnt; i += 256) {
        const int c = cols[e0 + i];
        const int r = rows[e0 + i];
        float w = ew[e0 + i];
        w = (w > 0.0f) ? w : 1e-7f;              // elu(w)<=0 <=> w<=0
        lcol[i] = (unsigned short)c;
        lrow[i] = (unsigned short)r;
        lw[i]   = f2bf(w);
        atomicAdd(&hist[c >> 8], 1);
    }
    __syncthreads();

    // exclusive scan of hist -> lofs
    {
        const int v = hist[tid];
        lofs[tid] = v;
        __syncthreads();
        for (int off = 1; off < 256; off <<= 1) {
            int t = (tid >= off) ? lofs[tid - off] : 0;
            __syncthreads();
            lofs[tid] += t;
            __syncthreads();
        }
        const int excl = lofs[tid] - v;
        __syncthreads();
        lofs[tid] = excl;
        __syncthreads();
    }

    // rank within block -> sorted index
    for (int i = tid; i < cnt; i += 256) {
        const int b = lcol[i] >> 8;
        const int pos = lofs[b] + atomicAdd(&fill[b], 1);
        sidx[pos] = (unsigned short)i;
    }
    __syncthreads();

    // reserve global space: one atomic per non-empty bucket
    {
        const int h = hist[tid];
        gbase[tid] = (h > 0) ? atomicAdd(&tails[tid], h) : 0;
    }
    __syncthreads();

    // write out in bucket-sorted order (runs of consecutive addresses)
    for (int i = tid; i < cnt; i += 256) {
        const int e = sidx[i];
        const int b = lcol[e] >> 8;
        const int slot = gbase[b] + (i - lofs[b]);
        if (slot < CAP) {                         // overflow guard
            const int addr = b * CAP + slot;
            bwr[addr] = ((unsigned int)lw[e] << 16) | lrow[e];
            bcl[addr] = (unsigned char)(lcol[e] & 255);
        }
    }
}

// ---- passB: per-bucket LDS sort + dis/starts/ends; coalesced meta write ----
__global__ __launch_bounds__(256) void k_passB(
    const unsigned int* __restrict__ bwr, const unsigned char* __restrict__ bcl,
    const int* __restrict__ tails,
    unsigned int* __restrict__ meta, int* __restrict__ starts,
    int* __restrict__ ends, float* __restrict__ dis, int N)
{
    const int tid  = threadIdx.x;
    const int b    = blockIdx.x;
    const int base = b * CAP;
    const int cnt  = min(tails[b], CAP);

    __shared__ unsigned int  lwr[CAP];      // 32 KB
    __shared__ unsigned char lcl[CAP];      // 8 KB
    __shared__ unsigned int  srt[CAP];      // 32 KB
    __shared__ int hist[256], offs[256], fill[256];

    hist[tid] = 0; fill[tid] = 0;
    __syncthreads();

    for (int i = tid; i < cnt; i += 256) {
        lwr[i] = bwr[base + i];
        unsigned char c = bcl[base + i];
        lcl[i] = c;
        atomicAdd(&hist[c], 1);
    }
    __syncthreads();

    // exclusive scan of hist -> offs
    {
        const int v = hist[tid];
        offs[tid] = v;
        __syncthreads();
        for (int off = 1; off < 256; off <<= 1) {
            int t = (tid >= off) ? offs[tid - off] : 0;
            __syncthreads();
            offs[tid] += t;
            __syncthreads();
        }
        const int excl = offs[tid] - v;
        __syncthreads();
        offs[tid] = excl;
        __syncthreads();
    }

    // scatter to sorted order (LDS -> LDS)
    for (int i = tid; i < cnt; i += 256) {
        const int c = lcl[i];
        const int pos = offs[c] + atomicAdd(&fill[c], 1);
        srt[pos] = lwr[i];
    }
    __syncthreads();

    // coalesced meta write
    for (int i = tid; i < cnt; i += 256) meta[base + i] = srt[i];

    // per-node: dis = rsqrt(1 + sum w), starts/ends
    const int node = b * BK + tid;
    if (node < N) {
        const int s = offs[tid];
        const int t = s + hist[tid];
        float sum = 1.0f;                         // self-loop
        for (int j = s; j < t; ++j) sum += bf_hi(srt[j]);
        dis[node]    = rsqrtf(sum);
        starts[node] = base + s;
        ends[node]   = base + t;
    }
}

// ---- z[r][:] = permuted bf16( dis[r] * (x[r] @ W^T) ) via MFMA ----
// r14: no min-waves cap; async LDS staging; in-loop W; coalesced uint2 store.
__global__ __launch_bounds__(256) void k_transform_mfma(
    const float* __restrict__ x, const unsigned short* __restrict__ Wbf,
    const float* __restrict__ dis, void* __restrict__ z, int N)
{
    constexpr int RB = 32;
    __shared__ float xs[RB][256];       // 32 KB, LINEAR (global_load_lds dest)

    const int tid  = threadIdx.x;
    const int r0   = blockIdx.x * RB;
    const int wave = tid >> 6;
    const int lane = tid & 63;
    const int lr   = lane & 15;     // A-row / D-col within tile
    const int kg   = lane >> 4;     // k-group (8 consecutive k each)
    const int nb   = (wave & 1) * 4;    // n-tile base (col half)
    const int wr0  = (wave >> 1) * 16;  // row offset within block (0 or 16)

    // ---- async stage: wave w stages rows 8w..8w+7, 1 KB per instruction.
    // Global source pre-swizzled (lane*16 ^ (row&7)<<4); LDS stays linear.
#pragma unroll
    for (int r = 0; r < 8; ++r) {
        const int row  = wave * 8 + r;
        const int grow = r0 + row;
        if (grow < N) {
            const char* src = (const char*)(x + (size_t)grow * 256)
                              + ((lane * 16) ^ ((row & 7) << 4));
            async_load16(src, &xs[row][0]);
        } else {
            *(float4*)((char*)&xs[row][0] + lane * 16) =
                make_float4(0.f, 0.f, 0.f, 0.f);
        }
    }
    __syncthreads();   // compiler inserts s_waitcnt vmcnt(0) before barrier

    f32x4_t acc[4];
#pragma unroll
    for (int n = 0; n < 4; ++n) acc[n] = (f32x4_t){0.f, 0.f, 0.f, 0.f};

    const char* xb  = (const char*)&xs[0][0];
    const int   row = wr0 + lr;
    const int   sw  = (row & 7) << 4;

#pragma unroll
    for (int k = 0; k < 8; ++k) {
        // want global bytes [g, g+32) of this row; LDS[p] = global[p^sw]
        const int g  = k * 128 + kg * 32;
        const int a0 = row * 1024 + (g ^ sw);
        const int a1 = row * 1024 + ((g + 16) ^ sw);
        float4 f0 = *(const float4*)(xb + a0);
        float4 f1 = *(const float4*)(xb + a1);
        short8_t af;
        af[0] = (short)f2bf(f0.x); af[1] = (short)f2bf(f0.y);
        af[2] = (short)f2bf(f0.z); af[3] = (short)f2bf(f0.w);
        af[4] = (short)f2bf(f1.x); af[5] = (short)f2bf(f1.y);
        af[6] = (short)f2bf(f1.z); af[7] = (short)f2bf(f1.w);
#pragma unroll
        for (int n = 0; n < 4; ++n) {
            const short8_t bf = *reinterpret_cast<const short8_t*>(
                Wbf + (size_t)((nb + n) * 16 + lr) * 256 + k * 32 + kg * 8);
            acc[n] = __builtin_amdgcn_mfma_f32_16x16x32_bf16(af, bf,
                                                             acc[n], 0, 0, 0);
        }
    }

    // permuted store: thread's 4 n-values are CONTIGUOUS shorts at
    // p = (wave&1)*64 + lr*4 + n  ->  one uint2 (8B) per row.
    // col(p) identity: 64h + n*16 + lr  (verified mapping in header).
    char* zb = (char*)z;
    float dsc[4];
#pragma unroll
    for (int r = 0; r < 4; ++r) {
        const int orow = r0 + wr0 + kg * 4 + r;
        dsc[r] = (orow < N) ? dis[orow] : 0.f;
    }
#pragma unroll
    for (int r = 0; r < 4; ++r) {
        const int orow = r0 + wr0 + kg * 4 + r;
        if (orow < N) {
            const float s = dsc[r];
            unsigned int lo = (unsigned int)f2bf(s * acc[0][r]) |
                              ((unsigned int)f2bf(s * acc[1][r]) << 16);
            unsigned int hi = (unsigned int)f2bf(s * acc[2][r]) |
                              ((unsigned int)f2bf(s * acc[3][r]) << 16);
            *(uint2*)(zb + (size_t)orow * 256 + (wave & 1) * 128 + lr * 8) =
                make_uint2(lo, hi);
        }
    }
}

// ---- hop: one wave per dst node, unroll-8 independent gathers ----
// Works in permuted-column space (elementwise). FINAL unwinds permutation:
// lane's u32 = shorts p0=2*lane (-> ax) and p0+1 (-> ay);
// col(p0) = 64*(lane>=32) + 32*(lane&1) + ((lane&31)>>1); col(p1)=col(p0)+16.
template <bool FINAL>
__global__ __launch_bounds__(256) void k_hop(
    const int* __restrict__ starts, const int* __restrict__ ends,
    const unsigned int* __restrict__ meta,
    const float* __restrict__ dis, const unsigned int* __restrict__ hin,
    const float* __restrict__ bias, void* __restrict__ hout, int N)
{
    const int wave = threadIdx.x >> 6;
    const int lane = threadIdx.x & 63;
    const int node = blockIdx.x * 4 + wave;
    if (node >= N) return;

    const int s = __builtin_amdgcn_readfirstlane(starts[node]);
    const int t = __builtin_amdgcn_readfirstlane(ends[node]);
    const float d = dis[node];

    unsigned int v = hin[(size_t)node * 64 + lane];
    float ax = bf_lo(v), ay = bf_hi(v);            // self term z[c]

    int j = s;
    for (; j + 8 <= t; j += 8) {
        unsigned int m0 = meta[j],     m1 = meta[j + 1];
        unsigned int m2 = meta[j + 2], m3 = meta[j + 3];
        unsigned int m4 = meta[j + 4], m5 = meta[j + 5];
        unsigned int m6 = meta[j + 6], m7 = meta[j + 7];
        unsigned int u0 = hin[(size_t)(m0 & 0xffffu) * 64 + lane];
        unsigned int u1 = hin[(size_t)(m1 & 0xffffu) * 64 + lane];
        unsigned int u2 = hin[(size_t)(m2 & 0xffffu) * 64 + lane];
        unsigned int u3 = hin[(size_t)(m3 & 0xffffu) * 64 + lane];
        unsigned int u4 = hin[(size_t)(m4 & 0xffffu) * 64 + lane];
        unsigned int u5 = hin[(size_t)(m5 & 0xffffu) * 64 + lane];
        unsigned int u6 = hin[(size_t)(m6 & 0xffffu) * 64 + lane];
        unsigned int u7 = hin[(size_t)(m7 & 0xffffu) * 64 + lane];
        ax += bf_hi(m0) * bf_lo(u0); ay += bf_hi(m0) * bf_hi(u0);
        ax += bf_hi(m1) * bf_lo(u1); ay += bf_hi(m1) * bf_hi(u1);
        ax += bf_hi(m2) * bf_lo(u2); ay += bf_hi(m2) * bf_hi(u2);
        ax += bf_hi(m3) * bf_lo(u3); ay += bf_hi(m3) * bf_hi(u3);
        ax += bf_hi(m4) * bf_lo(u4); ay += bf_hi(m4) * bf_hi(u4);
        ax += bf_hi(m5) * bf_lo(u5); ay += bf_hi(m5) * bf_hi(u5);
        ax += bf_hi(m6) * bf_lo(u6); ay += bf_hi(m6) * bf_hi(u6);
        ax += bf_hi(m7) * bf_lo(u7); ay += bf_hi(m7) * bf_hi(u7);
    }
    for (; j < t; ++j) {
        unsigned int m = meta[j];
        const float w = bf_hi(m);
        unsigned int u = hin[(size_t)(m & 0xffffu) * 64 + lane];
        ax += w * bf_lo(u); ay += w * bf_hi(u);
    }

    if (FINAL) {
        const int c0 = ((lane & 32) ? 64 : 0) + 32 * (lane & 1) +
                       ((lane & 31) >> 1);
        float* orow = (float*)hout + (size_t)node * 128;
        orow[c0]      = d * ax + bias[c0];
        orow[c0 + 16] = d * ay + bias[c0 + 16];
    } else {
        const float d2 = d * d;
        unsigned int p = (unsigned int)f2bf(d2 * ax) |
                         ((unsigned int)f2bf(d2 * ay) << 16);
        reinterpret_cast<unsigned int*>(hout)[(size_t)node * 64 + lane] = p;
    }
}

extern "C" void kernel_launch(void* const* d_in, const int* in_sizes, int n_in,
                              void* d_out, int out_size, void* d_ws, size_t ws_size,
                              hipStream_t stream)
{
    const float* x  = (const float*)d_in[0];
    const int*   ei = (const int*)d_in[1];     // int32 (harness converts)
    const float* ew = (const float*)d_in[2];
    const float* W  = (const float*)d_in[3];
    const float* b  = (const float*)d_in[4];

    const int E  = in_sizes[2];
    const int H  = in_sizes[4];        // 128
    const int T  = in_sizes[3] / H;    // 256
    const int N  = in_sizes[0] / T;    // 50000  (< 65536: 16-bit ids valid)
    const int WT = in_sizes[3];        // 32768
    const int NB = (N + BK - 1) / BK;  // 196 buckets

    const int* rows = ei;              // sources
    const int* cols = ei + E;          // targets (aggregation index)

    // ---- workspace ----
    char* wsb = (char*)d_ws;
    unsigned int*   z    = (unsigned int*)wsb;   wsb += (size_t)N * (H / 2) * 4;  // 12.8 MB
    unsigned int*   z1   = (unsigned int*)wsb;   wsb += (size_t)N * (H / 2) * 4;  // 12.8 MB
    unsigned int*   meta = (unsigned int*)wsb;   wsb += (size_t)NB * CAP * 4;     // 6.4 MB
    unsigned short* Wbf  = (unsigned short*)wsb; wsb += (size_t)WT * 2;           // 64 KB
    float*          dis  = (float*)wsb;          wsb += (size_t)N * 4;
    int*            sta  = (int*)wsb;            wsb += (size_t)N * 4;
    int*            end_ = (int*)wsb;            wsb += (size_t)N * 4;
    int*            tails= (int*)wsb;            wsb += (size_t)NB * 4;
    // bucket staging aliases z1 (dead until hop1 output): bwr 6.4MB + bcl 1.6MB
    unsigned int*   bwr  = z1;                                  // NB*CAP*4
    unsigned char*  bcl  = (unsigned char*)(z1 + (size_t)NB * CAP);

    float* out = (float*)d_out;

    // CSR build: bucket two-pass
    k_zero<<<(NB + 255) / 256, 256, 0, stream>>>(tails, NB);
    {
        const int nblkA = (E + CHUNK - 1) / CHUNK;   // 196 (covers WT too)
        k_passA<<<nblkA, 256, 0, stream>>>(rows, cols, ew, E,
                                           bwr, bcl, tails, W, Wbf, WT);
        k_passB<<<NB, 256, 0, stream>>>(bwr, bcl, tails,
                                        meta, sta, end_, dis, N);
    }

    // transform: z = permuted bf16(dis * (X W^T))
    {
        const int RB = 32;
        k_transform_mfma<<<(N + RB - 1) / RB, 256, 0, stream>>>(
            x, Wbf, dis, z, N);
    }

    // hops (hop1 overwrites z1 -> bucket staging dead by then)
    const int gH = (N + 3) / 4;
    k_hop<false><<<gH, 256, 0, stream>>>(sta, end_, meta, dis, z, nullptr, z1, N);
    k_hop<true ><<<gH, 256, 0, stream>>>(sta, end_, meta, dis, z1, b, out, N);
}

// Round 15
// 133.863 us; speedup vs baseline: 1.0446x; 1.0108x over previous
//
#include <hip/hip_runtime.h>

// ---------------------------------------------------------------------------
// SGConv (K=2): out = A^2 (X W^T) + b,  A = D^{-1/2}(Adj_clamped + I)D^{-1/2}
// N=50000, E=800000, T=256, H=128. edge_index arrives as int32.
//
// r15: the 7-variant invariant was W loads INSIDE the k-loop (compiler sank
// every "preload"; VGPR 44-92 proved it). Fix: asm volatile("" : "+v"(wf))
// after the preload forces the 32 W fragments to materialize in VGPRs
// (~190 VGPR total). k-loop is then pure LDS(x) + VGPR(W) + MFMA.
// x staged async via global_load_lds with xor-swizzled global source (r13).
// CSR build: two-pass bucket sort (r8). Hops: unroll-8 gather (r7/r14).
// z kept in MFMA-permuted layout (r14); hop2 unwinds analytically.
// ---------------------------------------------------------------------------

typedef __attribute__((ext_vector_type(8))) short short8_t;   // 8 bf16
typedef __attribute__((ext_vector_type(4))) float f32x4_t;    // MFMA acc

constexpr int BK    = 256;   // nodes per bucket
constexpr int CAP   = 8192;  // records per bucket (mean 4096 + 64 sigma)
constexpr int CHUNK = 4096;  // edges per passA block

__device__ inline unsigned short f2bf(float f) {               // RNE f32->bf16
    unsigned int u = __float_as_uint(f);
    return (unsigned short)((u + 0x7fffu + ((u >> 16) & 1u)) >> 16);
}
__device__ inline float bf_lo(unsigned int u) { return __uint_as_float(u << 16); }
__device__ inline float bf_hi(unsigned int u) { return __uint_as_float(u & 0xffff0000u); }

// async 16B/lane global->LDS (wave-uniform LDS base + lane*16)
__device__ inline void async_load16(const void* g, void* l) {
    __builtin_amdgcn_global_load_lds(
        (const __attribute__((address_space(1))) unsigned int*)g,
        (__attribute__((address_space(3))) unsigned int*)l, 16, 0, 0);
}

// ---- zero the bucket tails ----
__global__ __launch_bounds__(256) void k_zero(int* __restrict__ p, int n)
{
    int i = blockIdx.x * 256 + threadIdx.x;
    if (i < n) p[i] = 0;
}

// ---- passA: bucket-bin edges; coalesced appends to bucket storage ----
__global__ __launch_bounds__(256) void k_passA(
    const int* __restrict__ rows, const int* __restrict__ cols,
    const float* __restrict__ ew, int E,
    unsigned int* __restrict__ bwr,   // [NB*CAP]  w<<16|row
    unsigned char* __restrict__ bcl,  // [NB*CAP]  col low byte
    int* __restrict__ tails,          // [NB]
    const float* __restrict__ W, unsigned short* __restrict__ Wbf, int WT)
{
    const int tid = threadIdx.x;
    const int gid = blockIdx.x * 256 + tid;
    if (gid < WT) Wbf[gid] = f2bf(W[gid]);       // fold W->bf16 conversion

    __shared__ unsigned short lcol[CHUNK], lrow[CHUNK], lw[CHUNK];
    __shared__ unsigned short sidx[CHUNK];
    __shared__ int hist[256], lofs[256], fill[256], gbase[256];

    const int e0  = blockIdx.x * CHUNK;
    const int cnt = min(CHUNK, E - e0);
    if (cnt <= 0) return;

    hist[tid] = 0; fill[tid] = 0;
    __syncthreads();

    for (int i = tid; i < cnt; i += 256) {
        const int c = cols[e0 + i];
        const int r = rows[e0 + i];
        float w = ew[e0 + i];
        w = (w > 0.0f) ? w : 1e-7f;              // elu(w)<=0 <=> w<=0
        lcol[i] = (unsigned short)c;
        lrow[i] = (unsigned short)r;
        lw[i]   = f2bf(w);
        atomicAdd(&hist[c >> 8], 1);
    }
    __syncthreads();

    // exclusive scan of hist -> lofs
    {
        const int v = hist[tid];
        lofs[tid] = v;
        __syncthreads();
        for (int off = 1; off < 256; off <<= 1) {
            int t = (tid >= off) ? lofs[tid - off] : 0;
            __syncthreads();
            lofs[tid] += t;
            __syncthreads();
        }
        const int excl = lofs[tid] - v;
        __syncthreads();
        lofs[tid] = excl;
        __syncthreads();
    }

    // rank within block -> sorted index
    for (int i = tid; i < cnt; i += 256) {
        const int b = lcol[i] >> 8;
        const int pos = lofs[b] + atomicAdd(&fill[b], 1);
        sidx[pos] = (unsigned short)i;
    }
    __syncthreads();

    // reserve global space: one atomic per non-empty bucket
    {
        const int h = hist[tid];
        gbase[tid] = (h > 0) ? atomicAdd(&tails[tid], h) : 0;
    }
    __syncthreads();

    // write out in bucket-sorted order (runs of consecutive addresses)
    for (int i = tid; i < cnt; i += 256) {
        const int e = sidx[i];
        const int b = lcol[e] >> 8;
        const int slot = gbase[b] + (i - lofs[b]);
        if (slot < CAP) {                         // overflow guard
            const int addr = b * CAP + slot;
            bwr[addr] = ((unsigned int)lw[e] << 16) | lrow[e];
            bcl[addr] = (unsigned char)(lcol[e] & 255);
        }
    }
}

// ---- passB: per-bucket LDS sort + dis/starts/ends; coalesced meta write ----
__global__ __launch_bounds__(256) void k_passB(
    const unsigned int* __restrict__ bwr, const unsigned char* __restrict__ bcl,
    const int* __restrict__ tails,
    unsigned int* __restrict__ meta, int* __restrict__ starts,
    int* __restrict__ ends, float* __restrict__ dis, int N)
{
    const int tid  = threadIdx.x;
    const int b    = blockIdx.x;
    const int base = b * CAP;
    const int cnt  = min(tails[b], CAP);

    __shared__ unsigned int  lwr[CAP];      // 32 KB
    __shared__ unsigned char lcl[CAP];      // 8 KB
    __shared__ unsigned int  srt[CAP];      // 32 KB
    __shared__ int hist[256], offs[256], fill[256];

    hist[tid] = 0; fill[tid] = 0;
    __syncthreads();

    for (int i = tid; i < cnt; i += 256) {
        lwr[i] = bwr[base + i];
        unsigned char c = bcl[base + i];
        lcl[i] = c;
        atomicAdd(&hist[c], 1);
    }
    __syncthreads();

    // exclusive scan of hist -> offs
    {
        const int v = hist[tid];
        offs[tid] = v;
        __syncthreads();
        for (int off = 1; off < 256; off <<= 1) {
            int t = (tid >= off) ? offs[tid - off] : 0;
            __syncthreads();
            offs[tid] += t;
            __syncthreads();
        }
        const int excl = offs[tid] - v;
        __syncthreads();
        offs[tid] = excl;
        __syncthreads();
    }

    // scatter to sorted order (LDS -> LDS)
    for (int i = tid; i < cnt; i += 256) {
        const int c = lcl[i];
        const int pos = offs[c] + atomicAdd(&fill[c], 1);
        srt[pos] = lwr[i];
    }
    __syncthreads();

    // coalesced meta write
    for (int i = tid; i < cnt; i += 256) meta[base + i] = srt[i];

    // per-node: dis = rsqrt(1 + sum w), starts/ends
    const int node = b * BK + tid;
    if (node < N) {
        const int s = offs[tid];
        const int t = s + hist[tid];
        float sum = 1.0f;                         // self-loop
        for (int j = s; j < t; ++j) sum += bf_hi(srt[j]);
        dis[node]    = rsqrtf(sum);
        starts[node] = base + s;
        ends[node]   = base + t;
    }
}

// ---- z[r][:] = permuted bf16( dis[r] * (x[r] @ W^T) ) via MFMA ----
// r15: W fragments pinned in VGPRs via asm keep-alive; pure LDS/reg k-loop.
__global__ __launch_bounds__(256) void k_transform_mfma(
    const float* __restrict__ x, const unsigned short* __restrict__ Wbf,
    const float* __restrict__ dis, void* __restrict__ z, int N)
{
    constexpr int RB = 32;
    __shared__ float xs[RB][256];       // 32 KB, LINEAR (global_load_lds dest)

    const int tid  = threadIdx.x;
    const int r0   = blockIdx.x * RB;
    const int wave = tid >> 6;
    const int lane = tid & 63;
    const int lr   = lane & 15;     // A-row / D-col within tile
    const int kg   = lane >> 4;     // k-group (8 consecutive k each)
    const int nb   = (wave & 1) * 4;    // n-tile base (col half)
    const int wr0  = (wave >> 1) * 16;  // row offset within block (0 or 16)

    // ---- async stage: wave w stages rows 8w..8w+7, 1 KB per instruction.
    // Global source pre-swizzled (lane*16 ^ (row&7)<<4); LDS stays linear.
#pragma unroll
    for (int r = 0; r < 8; ++r) {
        const int row  = wave * 8 + r;
        const int grow = r0 + row;
        if (grow < N) {
            const char* src = (const char*)(x + (size_t)grow * 256)
                              + ((lane * 16) ^ ((row & 7) << 4));
            async_load16(src, &xs[row][0]);
        } else {
            *(float4*)((char*)&xs[row][0] + lane * 16) =
                make_float4(0.f, 0.f, 0.f, 0.f);
        }
    }

    // ---- W preload: 32 independent 16B loads, then FORCE materialization.
    short8_t wf[4][8];
#pragma unroll
    for (int n = 0; n < 4; ++n)
#pragma unroll
        for (int k = 0; k < 8; ++k)
            wf[n][k] = *reinterpret_cast<const short8_t*>(
                Wbf + (size_t)((nb + n) * 16 + lr) * 256 + k * 32 + kg * 8);
    // asm read+write pins each fragment in VGPRs here — the compiler cannot
    // sink the loads into the k-loop past this point (r10-r12 failure mode).
#pragma unroll
    for (int n = 0; n < 4; ++n)
#pragma unroll
        for (int k = 0; k < 8; ++k)
            asm volatile("" : "+v"(wf[n][k]));

    __syncthreads();   // drains vmcnt(0): staging + W loads complete

    f32x4_t acc[4];
#pragma unroll
    for (int n = 0; n < 4; ++n) acc[n] = (f32x4_t){0.f, 0.f, 0.f, 0.f};

    const char* xb  = (const char*)&xs[0][0];
    const int   row = wr0 + lr;
    const int   sw  = (row & 7) << 4;

#pragma unroll
    for (int k = 0; k < 8; ++k) {
        // want global bytes [g, g+32) of this row; LDS[p] = global[p^sw]
        const int g  = k * 128 + kg * 32;
        const int a0 = row * 1024 + (g ^ sw);
        const int a1 = row * 1024 + ((g + 16) ^ sw);
        float4 f0 = *(const float4*)(xb + a0);
        float4 f1 = *(const float4*)(xb + a1);
        short8_t af;
        af[0] = (short)f2bf(f0.x); af[1] = (short)f2bf(f0.y);
        af[2] = (short)f2bf(f0.z); af[3] = (short)f2bf(f0.w);
        af[4] = (short)f2bf(f1.x); af[5] = (short)f2bf(f1.y);
        af[6] = (short)f2bf(f1.z); af[7] = (short)f2bf(f1.w);
#pragma unroll
        for (int n = 0; n < 4; ++n)
            acc[n] = __builtin_amdgcn_mfma_f32_16x16x32_bf16(af, wf[n][k],
                                                             acc[n], 0, 0, 0);
    }

    // permuted store: thread's 4 n-values are CONTIGUOUS shorts at
    // p = (wave&1)*64 + lr*4 + n  ->  one uint2 (8B) per row.
    char* zb = (char*)z;
    float dsc[4];
#pragma unroll
    for (int r = 0; r < 4; ++r) {
        const int orow = r0 + wr0 + kg * 4 + r;
        dsc[r] = (orow < N) ? dis[orow] : 0.f;
    }
#pragma unroll
    for (int r = 0; r < 4; ++r) {
        const int orow = r0 + wr0 + kg * 4 + r;
        if (orow < N) {
            const float s = dsc[r];
            unsigned int lo = (unsigned int)f2bf(s * acc[0][r]) |
                              ((unsigned int)f2bf(s * acc[1][r]) << 16);
            unsigned int hi = (unsigned int)f2bf(s * acc[2][r]) |
                              ((unsigned int)f2bf(s * acc[3][r]) << 16);
            *(uint2*)(zb + (size_t)orow * 256 + (wave & 1) * 128 + lr * 8) =
                make_uint2(lo, hi);
        }
    }
}

// ---- hop: one wave per dst node, unroll-8 independent gathers ----
// Works in permuted-column space (elementwise). FINAL unwinds permutation:
// lane's u32 = shorts p0=2*lane (-> ax) and p0+1 (-> ay);
// col(p0) = 64*(lane>=32) + 32*(lane&1) + ((lane&31)>>1); col(p1)=col(p0)+16.
template <bool FINAL>
__global__ __launch_bounds__(256) void k_hop(
    const int* __restrict__ starts, const int* __restrict__ ends,
    const unsigned int* __restrict__ meta,
    const float* __restrict__ dis, const unsigned int* __restrict__ hin,
    const float* __restrict__ bias, void* __restrict__ hout, int N)
{
    const int wave = threadIdx.x >> 6;
    const int lane = threadIdx.x & 63;
    const int node = blockIdx.x * 4 + wave;
    if (node >= N) return;

    const int s = __builtin_amdgcn_readfirstlane(starts[node]);
    const int t = __builtin_amdgcn_readfirstlane(ends[node]);
    const float d = dis[node];

    unsigned int v = hin[(size_t)node * 64 + lane];
    float ax = bf_lo(v), ay = bf_hi(v);            // self term z[c]

    int j = s;
    for (; j + 8 <= t; j += 8) {
        unsigned int m0 = meta[j],     m1 = meta[j + 1];
        unsigned int m2 = meta[j + 2], m3 = meta[j + 3];
        unsigned int m4 = meta[j + 4], m5 = meta[j + 5];
        unsigned int m6 = meta[j + 6], m7 = meta[j + 7];
        unsigned int u0 = hin[(size_t)(m0 & 0xffffu) * 64 + lane];
        unsigned int u1 = hin[(size_t)(m1 & 0xffffu) * 64 + lane];
        unsigned int u2 = hin[(size_t)(m2 & 0xffffu) * 64 + lane];
        unsigned int u3 = hin[(size_t)(m3 & 0xffffu) * 64 + lane];
        unsigned int u4 = hin[(size_t)(m4 & 0xffffu) * 64 + lane];
        unsigned int u5 = hin[(size_t)(m5 & 0xffffu) * 64 + lane];
        unsigned int u6 = hin[(size_t)(m6 & 0xffffu) * 64 + lane];
        unsigned int u7 = hin[(size_t)(m7 & 0xffffu) * 64 + lane];
        ax += bf_hi(m0) * bf_lo(u0); ay += bf_hi(m0) * bf_hi(u0);
        ax += bf_hi(m1) * bf_lo(u1); ay += bf_hi(m1) * bf_hi(u1);
        ax += bf_hi(m2) * bf_lo(u2); ay += bf_hi(m2) * bf_hi(u2);
        ax += bf_hi(m3) * bf_lo(u3); ay += bf_hi(m3) * bf_hi(u3);
        ax += bf_hi(m4) * bf_lo(u4); ay += bf_hi(m4) * bf_hi(u4);
        ax += bf_hi(m5) * bf_lo(u5); ay += bf_hi(m5) * bf_hi(u5);
        ax += bf_hi(m6) * bf_lo(u6); ay += bf_hi(m6) * bf_hi(u6);
        ax += bf_hi(m7) * bf_lo(u7); ay += bf_hi(m7) * bf_hi(u7);
    }
    for (; j < t; ++j) {
        unsigned int m = meta[j];
        const float w = bf_hi(m);
        unsigned int u = hin[(size_t)(m & 0xffffu) * 64 + lane];
        ax += w * bf_lo(u); ay += w * bf_hi(u);
    }

    if (FINAL) {
        const int c0 = ((lane & 32) ? 64 : 0) + 32 * (lane & 1) +
                       ((lane & 31) >> 1);
        float* orow = (float*)hout + (size_t)node * 128;
        orow[c0]      = d * ax + bias[c0];
        orow[c0 + 16] = d * ay + bias[c0 + 16];
    } else {
        const float d2 = d * d;
        unsigned int p = (unsigned int)f2bf(d2 * ax) |
                         ((unsigned int)f2bf(d2 * ay) << 16);
        reinterpret_cast<unsigned int*>(hout)[(size_t)node * 64 + lane] = p;
    }
}

extern "C" void kernel_launch(void* const* d_in, const int* in_sizes, int n_in,
                              void* d_out, int out_size, void* d_ws, size_t ws_size,
                              hipStream_t stream)
{
    const float* x  = (const float*)d_in[0];
    const int*   ei = (const int*)d_in[1];     // int32 (harness converts)
    const float* ew = (const float*)d_in[2];
    const float* W  = (const float*)d_in[3];
    const float* b  = (const float*)d_in[4];

    const int E  = in_sizes[2];
    const int H  = in_sizes[4];        // 128
    const int T  = in_sizes[3] / H;    // 256
    const int N  = in_sizes[0] / T;    // 50000  (< 65536: 16-bit ids valid)
    const int WT = in_sizes[3];        // 32768
    const int NB = (N + BK - 1) / BK;  // 196 buckets

    const int* rows = ei;              // sources
    const int* cols = ei + E;          // targets (aggregation index)

    // ---- workspace ----
    char* wsb = (char*)d_ws;
    unsigned int*   z    = (unsigned int*)wsb;   wsb += (size_t)N * (H / 2) * 4;  // 12.8 MB
    unsigned int*   z1   = (unsigned int*)wsb;   wsb += (size_t)N * (H / 2) * 4;  // 12.8 MB
    unsigned int*   meta = (unsigned int*)wsb;   wsb += (size_t)NB * CAP * 4;     // 6.4 MB
    unsigned short* Wbf  = (unsigned short*)wsb; wsb += (size_t)WT * 2;           // 64 KB
    float*          dis  = (float*)wsb;          wsb += (size_t)N * 4;
    int*            sta  = (int*)wsb;            wsb += (size_t)N * 4;
    int*            end_ = (int*)wsb;            wsb += (size_t)N * 4;
    int*            tails= (int*)wsb;            wsb += (size_t)NB * 4;
    // bucket staging aliases z1 (dead until hop1 output): bwr 6.4MB + bcl 1.6MB
    unsigned int*   bwr  = z1;                                  // NB*CAP*4
    unsigned char*  bcl  = (unsigned char*)(z1 + (size_t)NB * CAP);

    float* out = (float*)d_out;

    // CSR build: bucket two-pass
    k_zero<<<(NB + 255) / 256, 256, 0, stream>>>(tails, NB);
    {
        const int nblkA = (E + CHUNK - 1) / CHUNK;   // 196 (covers WT too)
        k_passA<<<nblkA, 256, 0, stream>>>(rows, cols, ew, E,
                                           bwr, bcl, tails, W, Wbf, WT);
        k_passB<<<NB, 256, 0, stream>>>(bwr, bcl, tails,
                                        meta, sta, end_, dis, N);
    }

    // transform: z = permuted bf16(dis * (X W^T))
    {
        const int RB = 32;
        k_transform_mfma<<<(N + RB - 1) / RB, 256, 0, stream>>>(
            x, Wbf, dis, z, N);
    }

    // hops (hop1 overwrites z1 -> bucket staging dead by then)
    const int gH = (N + 3) / 4;
    k_hop<false><<<gH, 256, 0, stream>>>(sta, end_, meta, dis, z, nullptr, z1, N);
    k_hop<true ><<<gH, 256, 0, stream>>>(sta, end_, meta, dis, z1, b, out, N);
}